// Round 12
// baseline (343.751 us; speedup 1.0000x reference)
//
#include <hip/hip_runtime.h>
#include <hip/hip_bf16.h>

// BiLSTM-CRF fused pipeline for MI355X (gfx950).
// R12: (1) Ap materialization eliminated -- pack builds a bf16 K-padded
// embedding TABLE embP (11626x320, 7.4MB, L2/L3-hot) and gemm's A-staging
// gathers rows via per-thread token indices straight into global_load_lds.
// pack grid 50.4k -> 13.7k blocks. (2) crf interleaves 2 independent batch
// rows per lane (grid 128): two alpha-chains per wave hide each other's
// shuffle/exp latency bubbles. lstm (107us measured floor) and gemm core
// unchanged from R11.

#define B_   256
#define T_   192
#define E_   300
#define KP   320   // padded K
#define V_   11626
#define H_   128
#define G4   512   // 4*H
#define NG   1024  // both directions
#define NT_  13
#define NEGV -10000.0f
#define HSTR 144   // hL row stride in ushorts (288B, 16B-aligned)

typedef __attribute__((ext_vector_type(8))) short bf16x8;
typedef __attribute__((ext_vector_type(4))) float f32x4;
typedef __attribute__((ext_vector_type(4))) unsigned short u16x4;

__device__ __forceinline__ unsigned short f2bf(float f) {
    return (unsigned short)(__float_as_uint(f) >> 16);   // truncation: ample threshold
}
__device__ __forceinline__ float bf2f(unsigned short h) {
    return __uint_as_float(((unsigned)h) << 16);
}
__device__ __forceinline__ float sigf(float x) {
    return __builtin_amdgcn_rcpf(1.0f + __expf(-x));
}
__device__ __forceinline__ float tanhfast(float x) {
    return __builtin_amdgcn_rcpf(1.0f + __expf(-2.0f * x)) * 2.0f - 1.0f;
}
__device__ __forceinline__ void barrier_lgkm() {
    // LDS-visibility barrier WITHOUT the forced vmcnt(0) drain of __syncthreads
    asm volatile("s_waitcnt lgkmcnt(0)\n\ts_barrier" ::: "memory");
}

// ------- pack W_ih + W_hh (frag order) + emb table (K-padded bf16) -----------
__global__ void pack_kernel(const float* __restrict__ Wf, const float* __restrict__ Wb,
                            const float* __restrict__ Whf, const float* __restrict__ Whb,
                            const float* __restrict__ emb,
                            unsigned short* __restrict__ Wp, unsigned short* __restrict__ Whp,
                            unsigned short* __restrict__ Ep, float* __restrict__ out) {
    int blk = blockIdx.x;
    int k = threadIdx.x;
    if (blk == 0 && k == 0) out[0] = 0.0f;   // zero accumulator for crf atomicAdd
    if (blk < NG) {
        float v = 0.0f;
        if (k < E_) v = (blk < G4) ? Wf[blk * E_ + k] : Wb[(blk - G4) * E_ + k];
        Wp[blk * KP + k] = f2bf(v);
    } else if (blk < NG + 1024) {
        // W_hh -> bf16 fragment order: Whp[(((d*8+w)*4+j)*4+kc)*64 + lane]*8 + e
        int t = blk - NG;
        int d = t >> 9, g = t & 511;
        if (k < H_) {
            const float* src = d ? Whb : Whf;
            float v = src[g * H_ + k];
            int w = (g >> 4) & 7, j = g >> 7, colq = g & 15;
            int kc = k >> 5, quad = (k >> 3) & 3, e = k & 7;
            Whp[((((size_t)(d * 8 + w) * 4 + j) * 4 + kc) * 64 + quad * 16 + colq) * 8 + e] = f2bf(v);
        }
    } else {
        int r = blk - NG - 1024;             // vocab row 0..V_-1
        float v = (k < E_) ? emb[(size_t)r * E_ + k] : 0.0f;
        Ep[(size_t)r * KP + k] = f2bf(v);
    }
}

// ---------------- bf16 MFMA GEMM: gx = emb[sent] @ W^T + bias, permuted ------
// A-tiles gathered from the packed embedding table via token indices; both
// As and Bs staged with global_load_lds width=16 (no VGPR roundtrip).
__global__ __launch_bounds__(256, 3) void gemm_kernel(const unsigned short* __restrict__ Ep,
                                                      const int* __restrict__ sent,
                                                      const unsigned short* __restrict__ Bw,
                                                      const float* __restrict__ bF,
                                                      const float* __restrict__ bB,
                                                      unsigned short* __restrict__ C) {
    __shared__ __align__(16) unsigned short As[128 * 64];
    __shared__ __align__(16) unsigned short Bs[128 * 64];
    const int tid  = threadIdx.x;
    const int lane = tid & 63;
    const int wave = tid >> 6;
    const int wr = wave >> 1, wc = wave & 1;
    const int colL = lane & 15;
    const int mBase = blockIdx.y * 128;
    const int bx = blockIdx.x;
    const int d  = bx >> 2;
    const int w0 = (bx & 3) * 2;
    int toks[4];
    #pragma unroll
    for (int j = 0; j < 4; j++)
        toks[j] = sent[mBase + ((tid + 256 * j) >> 3)];
    f32x4 acc[4][4] = {};
    for (int k0 = 0; k0 < KP; k0 += 64) {
        #pragma unroll
        for (int j = 0; j < 4; j++) {
            int c   = tid + 256 * j;       // 16B chunk id 0..1023; LDS offset = c*16
            int row = c >> 3;
            int col = (c & 7) * 8;
            __builtin_amdgcn_global_load_lds(
                (const void*)(Ep + (size_t)toks[j] * KP + k0 + col),
                (void*)((char*)As + c * 16), 16, 0, 0);
            int ws = row >> 6, jj = (row >> 4) & 3, cc = row & 15;
            int srcrow = d * 512 + (8 * jj + w0 + ws) * 16 + cc;
            __builtin_amdgcn_global_load_lds(
                (const void*)(Bw + (size_t)srcrow * KP + k0 + col),
                (void*)((char*)Bs + c * 16), 16, 0, 0);
        }
        __syncthreads();
        #pragma unroll
        for (int ks = 0; ks < 2; ks++) {
            bf16x8 af[4], bfr[4];
            #pragma unroll
            for (int i = 0; i < 4; i++) {
                int arow = wr * 64 + i * 16 + colL;
                af[i]  = *(const bf16x8*)(As + arow * 64 + ks * 32 + (lane >> 4) * 8);
                int brow = wc * 64 + i * 16 + colL;
                bfr[i] = *(const bf16x8*)(Bs + brow * 64 + ks * 32 + (lane >> 4) * 8);
            }
            #pragma unroll
            for (int i = 0; i < 4; i++)
                #pragma unroll
                for (int n2 = 0; n2 < 4; n2++)
                    acc[i][n2] = __builtin_amdgcn_mfma_f32_16x16x32_bf16(af[i], bfr[n2], acc[i][n2], 0, 0, 0);
        }
        __syncthreads();
    }
    const float* bias_d = d ? bB : bF;
    float bj[4];
    #pragma unroll
    for (int n2 = 0; n2 < 4; n2++) bj[n2] = bias_d[(8 * n2 + w0 + wc) * 16 + colL];
    #pragma unroll
    for (int i = 0; i < 4; i++)
        #pragma unroll
        for (int r = 0; r < 4; r++) {
            int row = mBase + wr * 64 + i * 16 + (lane >> 4) * 4 + r;
            u16x4 v;
            #pragma unroll
            for (int n2 = 0; n2 < 4; n2++) v[n2] = f2bf(acc[i][n2][r] + bj[n2]);
            *(u16x4*)(C + (size_t)row * NG + d * 512 + (w0 + wc) * 64 + colL * 4) = v;
        }
}

// ---------------- MFMA LSTM recurrence + feats projection --------------------
// grid 128: block = (4 batch rows, dir). 576 threads = 9 waves (R7 structure).
__global__ __launch_bounds__(576, 1) void lstm_kernel(const unsigned short* __restrict__ gxP,
                                                      const unsigned short* __restrict__ Whp,
                                                      const int* __restrict__ seq_len,
                                                      const float* __restrict__ Wfc,
                                                      float* __restrict__ featsF,
                                                      float* __restrict__ featsB) {
    __shared__ __align__(16) unsigned short hL[2][16 * HSTR];
    __shared__ int Ls[4];
    __shared__ int maxLs;
    const int tid  = threadIdx.x;
    const int wave = tid >> 6;
    const int lane = tid & 63;
    const int col  = lane & 15;
    const int quad = lane >> 4;
    const int dir  = blockIdx.x & 1;
    const int b0   = (blockIdx.x >> 1) * 4;
    float* fOut = dir ? featsB : featsF;

    if (tid < 4) Ls[tid] = min(max(seq_len[b0 + tid], 1), T_);
    __syncthreads();
    if (tid == 0) { int m = 0; for (int i = 0; i < 4; i++) m = max(m, Ls[i]); maxLs = m; }
    __syncthreads();
    const int maxL = maxLs;
    const int Lq = Ls[quad];              // this lane's row length
    const int dNG = dir ? -NG : NG;

    bf16x8 Bf[4][4];                      // W_hh fragments (waves 0-7)
    bf16x8 Wf8[4];                        // W_fc fragments (wave 8)
    const unsigned short* rb = nullptr;   // this lane's gx base (step-0 pos)
    int ofs2 = 0;                         // element offset of the step-(s+2) load
    u16x4 gx0v = {}, gx1v = {};           // parity prefetch slots
    float* fb = nullptr;                  // wave-8 feats store base
    int foff = 0;

    if (wave < 8) {
        #pragma unroll
        for (int j = 0; j < 4; j++)
            #pragma unroll
            for (int kc = 0; kc < 4; kc++)
                Bf[j][kc] = *(const bf16x8*)(Whp +
                    ((((size_t)(dir * 8 + wave) * 4 + j) * 4 + kc) * 64 + lane) * 8);
        int row = b0 + quad;
        int p0 = dir ? (Lq - 1) : 0;
        rb = gxP + ((size_t)(row * T_ + p0)) * NG + dir * 512 + wave * 64 + col * 4;
        gx0v = *(const u16x4*)(rb);
        gx1v = *(const u16x4*)(rb + ((Lq > 1) ? dNG : 0));
        ofs2 = min(2, Lq - 1) * dNG;
    } else {
        #pragma unroll
        for (int kc = 0; kc < 4; kc++)
            #pragma unroll
            for (int e = 0; e < 8; e++) {
                float v = (col < NT_) ? Wfc[col * 256 + dir * H_ + kc * 32 + quad * 8 + e] : 0.0f;
                Wf8[kc][e] = (short)f2bf(v);
            }
        fb = fOut + (size_t)(b0 + quad) * T_ * NT_ + col;
        foff = (dir ? (Lq - 1) : 0) * NT_;
    }
    const int fd = dir ? -NT_ : NT_;

    float cst = 0.0f;
    bf16x8 Af[4];
    #pragma unroll
    for (int kc = 0; kc < 4; kc++)
        #pragma unroll
        for (int e = 0; e < 8; e++) Af[kc][e] = 0;   // h(-1) = 0

    auto step_body = [&](int s, u16x4& gxs, int par) {
        if (wave < 8) {
            f32x4 acc[4];
            #pragma unroll
            for (int j = 0; j < 4; j++) {
                acc[j][0] = bf2f(gxs[j]);            // gx (+bias) seed, real row
                acc[j][1] = 0.f; acc[j][2] = 0.f; acc[j][3] = 0.f;
            }
            // prefetch gx for step s+2 into the slot just consumed
            gxs = *(const u16x4*)(rb + ofs2);
            ofs2 = (s + 3 < Lq) ? ofs2 + dNG : ofs2;
            #pragma unroll
            for (int kc = 0; kc < 4; kc++)
                #pragma unroll
                for (int j = 0; j < 4; j++)
                    acc[j] = __builtin_amdgcn_mfma_f32_16x16x32_bf16(Af[kc], Bf[j][kc], acc[j], 0, 0, 0);
            float cn = sigf(acc[1][0]) * cst + sigf(acc[0][0]) * tanhfast(acc[2][0]);
            cst = cn;
            float hn = sigf(acc[3][0]) * tanhfast(cn);
            hL[par][(quad * 4) * HSTR + wave * 16 + col] = f2bf(hn);
        }
        barrier_lgkm();
        #pragma unroll
        for (int kc = 0; kc < 4; kc++)
            Af[kc] = *(const bf16x8*)(&hL[par][col * HSTR + kc * 32 + quad * 8]);
        if (wave == 8) {
            f32x4 fc = (f32x4){0.f, 0.f, 0.f, 0.f};
            #pragma unroll
            for (int kc = 0; kc < 4; kc++)
                fc = __builtin_amdgcn_mfma_f32_16x16x32_bf16(Af[kc], Wf8[kc], fc, 0, 0, 0);
            if (col < NT_ && s < Lq) fb[foff] = fc[0];
            foff += fd;
        }
    };

    for (int s = 0; s < maxL; s += 2) {
        step_body(s, gx0v, 0);
        if (s + 1 < maxL) step_body(s + 1, gx1v, 1);
    }
}

// ---------------- CRF: 2 batch rows per lane (ILP-2 chains), fused mean ------
// One wave per block, rows bA=2*blk, bB=2*blk+1. Each lane carries both
// alpha_j registers; the two independent recurrences interleave and hide
// each other's shuffle/exp latency. Feats for both rows staged one 16-step
// chunk ahead via float4 bulk loads (lanes 0..51).
__global__ __launch_bounds__(64) void crf_kernel(const float* __restrict__ fF,
                                                 const float* __restrict__ fB,
                                                 const float* __restrict__ bfc,
                                                 const float* __restrict__ trans,
                                                 const int* __restrict__ tags,
                                                 const int* __restrict__ seq_len,
                                                 float* __restrict__ out) {
    __shared__ __align__(16) float feat_lds[2][2][208];   // [parity][row][elem]
    __shared__ float Tlds[NT_ * NT_];
    const int lane = threadIdx.x;
    const int bA = blockIdx.x * 2, bB = bA + 1;
    const int LbA = min(max(seq_len[bA], 1), T_);
    const int LbB = min(max(seq_len[bB], 1), T_);
    const float* fF0 = fF + (size_t)bA * T_ * NT_;
    const float* fB0 = fB + (size_t)bA * T_ * NT_;
    const float* fF1 = fF + (size_t)bB * T_ * NT_;
    const float* fB1 = fB + (size_t)bB * T_ * NT_;
    const int* tgA = tags + (size_t)bA * T_;
    const int* tgB = tags + (size_t)bB * T_;

    for (int i = lane; i < NT_ * NT_; i += 64) Tlds[i] = trans[i];

    const int jc = min(lane, NT_ - 1);
    float Tj[NT_];
    #pragma unroll
    for (int i = 0; i < NT_; i++) Tj[i] = trans[jc * NT_ + i];
    const float bj  = bfc[jc];
    const float T10 = trans[10 * NT_ + jc];
    float alA = (lane == 0) ? 0.0f : NEGV;
    float alB = (lane == 0) ? 0.0f : NEGV;

    // stage chunk 0 for both rows
    const int e0 = lane * 4;
    const bool ldact = (lane < 52);
    float4 vF0 = {}, vB0 = {}, vF1 = {}, vB1 = {};
    if (ldact) {
        vF0 = *(const float4*)(fF0 + e0); vB0 = *(const float4*)(fB0 + e0);
        vF1 = *(const float4*)(fF1 + e0); vB1 = *(const float4*)(fB1 + e0);
    }

    #pragma unroll 1
    for (int c = 0; c < 12; ++c) {
        if (ldact) {
            float4 w0, w1;
            #pragma unroll
            for (int k = 0; k < 4; k++) {
                unsigned g = (unsigned)(c * 208 + e0 + k);
                unsigned t = g / 13u;
                float s0 = ((const float*)&vF0)[k] + ((const float*)&vB0)[k];
                float s1 = ((const float*)&vF1)[k] + ((const float*)&vB1)[k];
                ((float*)&w0)[k] = (t < (unsigned)LbA) ? s0 : 0.0f;
                ((float*)&w1)[k] = (t < (unsigned)LbB) ? s1 : 0.0f;
            }
            *(float4*)&feat_lds[c & 1][0][e0] = w0;
            *(float4*)&feat_lds[c & 1][1][e0] = w1;
            if (c < 11) {
                vF0 = *(const float4*)(fF0 + (c + 1) * 208 + e0);
                vB0 = *(const float4*)(fB0 + (c + 1) * 208 + e0);
                vF1 = *(const float4*)(fF1 + (c + 1) * 208 + e0);
                vB1 = *(const float4*)(fB1 + (c + 1) * 208 + e0);
            }
        }
        barrier_lgkm();
        const int par = c & 1;
        for (int tt = 0; tt < 16; ++tt) {
            float featA = feat_lds[par][0][tt * NT_ + jc];
            float featB = feat_lds[par][1][tt * NT_ + jc];
            float vA[NT_], vB_[NT_];
            #pragma unroll
            for (int i = 0; i < NT_; i++) {
                vA[i]  = __shfl(alA, i, 64) + Tj[i];
                vB_[i] = __shfl(alB, i, 64) + Tj[i];
            }
            float mA = vA[12], mB = vB_[12];
            #pragma unroll
            for (int i = 0; i < 12; i += 2) {
                mA = fmaxf(mA, fmaxf(vA[i], vA[i + 1]));
                mB = fmaxf(mB, fmaxf(vB_[i], vB_[i + 1]));
            }
            float sA = 0.0f, sB = 0.0f;
            #pragma unroll
            for (int i = 0; i < NT_; i++) {
                sA += __expf(vA[i] - mA);
                sB += __expf(vB_[i] - mB);
            }
            alA = mA + __logf(sA) + featA + bj;
            alB = mB + __logf(sB) + featB + bj;
        }
    }

    // gold scores: t = lane, lane+64, lane+128 for both rows
    float gpA = 0.0f, gpB = 0.0f;
    #pragma unroll
    for (int u = 0; u < 3; ++u) {
        int t = lane + u * 64;
        int ta = tgA[t];
        int pa = (t == 0) ? 0 : tgA[t - 1];
        float ea = bfc[ta];
        if (t < LbA) ea += fF0[t * NT_ + ta] + fB0[t * NT_ + ta];
        gpA += Tlds[ta * NT_ + pa] + ea;
        int tb = tgB[t];
        int pb = (t == 0) ? 0 : tgB[t - 1];
        float eb = bfc[tb];
        if (t < LbB) eb += fF1[t * NT_ + tb] + fB1[t * NT_ + tb];
        gpB += Tlds[tb * NT_ + pb] + eb;
    }
    #pragma unroll
    for (int o = 32; o > 0; o >>= 1) {
        gpA += __shfl_down(gpA, o, 64);
        gpB += __shfl_down(gpB, o, 64);
    }

    // fwd = LSE_j(alphaT[j] + trans[10][j]) per row
    float vjA = (lane < NT_) ? (alA + T10) : -3.0e38f;
    float vjB = (lane < NT_) ? (alB + T10) : -3.0e38f;
    float mmA = vjA, mmB = vjB;
    #pragma unroll
    for (int o = 32; o > 0; o >>= 1) {
        mmA = fmaxf(mmA, __shfl_down(mmA, o, 64));
        mmB = fmaxf(mmB, __shfl_down(mmB, o, 64));
    }
    mmA = __shfl(mmA, 0, 64);
    mmB = __shfl(mmB, 0, 64);
    float seA = (lane < NT_) ? __expf(vjA - mmA) : 0.0f;
    float seB = (lane < NT_) ? __expf(vjB - mmB) : 0.0f;
    #pragma unroll
    for (int o = 32; o > 0; o >>= 1) {
        seA += __shfl_down(seA, o, 64);
        seB += __shfl_down(seB, o, 64);
    }
    if (lane == 0) {
        float fwdA = mmA + __logf(seA);
        float fwdB = mmB + __logf(seB);
        float goldA = gpA + Tlds[10 * NT_ + tgA[T_ - 1]];
        float goldB = gpB + Tlds[10 * NT_ + tgB[T_ - 1]];
        atomicAdd(out, ((fwdA - goldA) + (fwdB - goldB)) * (1.0f / 256.0f));
    }
}

extern "C" void kernel_launch(void* const* d_in, const int* in_sizes, int n_in,
                              void* d_out, int out_size, void* d_ws, size_t ws_size,
                              hipStream_t stream) {
    const int*   sentence  = (const int*)d_in[0];
    const int*   seq_len   = (const int*)d_in[1];
    const int*   tags      = (const int*)d_in[2];
    const float* embedding = (const float*)d_in[3];
    const float* W_ih_f    = (const float*)d_in[4];
    const float* W_hh_f    = (const float*)d_in[5];
    const float* b_f       = (const float*)d_in[6];
    const float* W_ih_b    = (const float*)d_in[7];
    const float* W_hh_b    = (const float*)d_in[8];
    const float* b_b       = (const float*)d_in[9];
    const float* W_fc      = (const float*)d_in[10];
    const float* b_fc      = (const float*)d_in[11];
    const float* trans     = (const float*)d_in[12];
    float* out = (float*)d_out;

    char* ws = (char*)d_ws;
    const size_t M = (size_t)B_ * T_;                   // 49152
    unsigned short* Wp  = (unsigned short*)(ws);                         // 655,360
    unsigned short* Ep  = (unsigned short*)(ws + 655360);                // 11626*320*2 = 7,440,640
    unsigned short* gx  = (unsigned short*)(ws + 8096000);               // 100,663,296
    float* featsF = (float*)(ws + 108759296);                            // 2,555,904
    float* featsB = (float*)(ws + 111315200);                            // 2,555,904
    unsigned short* Whp = (unsigned short*)(ws + 113871104);             // 262,144

    pack_kernel<<<NG + 1024 + V_, KP, 0, stream>>>(W_ih_f, W_ih_b, W_hh_f, W_hh_b,
                                                   embedding, Wp, Whp, Ep, out);
    dim3 gg(8, (int)(M / 128));
    gemm_kernel<<<gg, 256, 0, stream>>>(Ep, sentence, Wp, b_f, b_b, gx);
    lstm_kernel<<<128, 576, 0, stream>>>(gx, Whp, seq_len, W_fc, featsF, featsB);
    crf_kernel<<<B_ / 2, 64, 0, stream>>>(featsF, featsB, b_fc, trans, tags, seq_len, out);
}

// Round 13
// 299.694 us; speedup vs baseline: 1.1470x; 1.1470x over previous
//
#include <hip/hip_runtime.h>
#include <hip/hip_bf16.h>

// BiLSTM-CRF fused pipeline for MI355X (gfx950).
// R13: compose best-known components. crf reverted to R11 exact (grid 256,
// one wave/row, alpha in registers via shuffles -- R12's 2-row interleave
// halved the grid and doubled per-block serial work: strictly worse wall
// time when CUs aren't scarce; measured +42us). Ep-gather gemm kept
// (R12 measured ~-28us). lstm untouched (107us measured floor).

#define B_   256
#define T_   192
#define E_   300
#define KP   320   // padded K
#define V_   11626
#define H_   128
#define G4   512   // 4*H
#define NG   1024  // both directions
#define NT_  13
#define NEGV -10000.0f
#define HSTR 144   // hL row stride in ushorts (288B, 16B-aligned)

typedef __attribute__((ext_vector_type(8))) short bf16x8;
typedef __attribute__((ext_vector_type(4))) float f32x4;
typedef __attribute__((ext_vector_type(4))) unsigned short u16x4;

__device__ __forceinline__ unsigned short f2bf(float f) {
    return (unsigned short)(__float_as_uint(f) >> 16);   // truncation: ample threshold
}
__device__ __forceinline__ float bf2f(unsigned short h) {
    return __uint_as_float(((unsigned)h) << 16);
}
__device__ __forceinline__ float sigf(float x) {
    return __builtin_amdgcn_rcpf(1.0f + __expf(-x));
}
__device__ __forceinline__ float tanhfast(float x) {
    return __builtin_amdgcn_rcpf(1.0f + __expf(-2.0f * x)) * 2.0f - 1.0f;
}
__device__ __forceinline__ void barrier_lgkm() {
    // LDS-visibility barrier WITHOUT the forced vmcnt(0) drain of __syncthreads
    asm volatile("s_waitcnt lgkmcnt(0)\n\ts_barrier" ::: "memory");
}

// ------- pack W_ih + W_hh (frag order) + emb table (K-padded bf16) -----------
__global__ void pack_kernel(const float* __restrict__ Wf, const float* __restrict__ Wb,
                            const float* __restrict__ Whf, const float* __restrict__ Whb,
                            const float* __restrict__ emb,
                            unsigned short* __restrict__ Wp, unsigned short* __restrict__ Whp,
                            unsigned short* __restrict__ Ep, float* __restrict__ out) {
    int blk = blockIdx.x;
    int k = threadIdx.x;
    if (blk == 0 && k == 0) out[0] = 0.0f;   // zero accumulator for crf atomicAdd
    if (blk < NG) {
        float v = 0.0f;
        if (k < E_) v = (blk < G4) ? Wf[blk * E_ + k] : Wb[(blk - G4) * E_ + k];
        Wp[blk * KP + k] = f2bf(v);
    } else if (blk < NG + 1024) {
        // W_hh -> bf16 fragment order: Whp[(((d*8+w)*4+j)*4+kc)*64 + lane]*8 + e
        int t = blk - NG;
        int d = t >> 9, g = t & 511;
        if (k < H_) {
            const float* src = d ? Whb : Whf;
            float v = src[g * H_ + k];
            int w = (g >> 4) & 7, j = g >> 7, colq = g & 15;
            int kc = k >> 5, quad = (k >> 3) & 3, e = k & 7;
            Whp[((((size_t)(d * 8 + w) * 4 + j) * 4 + kc) * 64 + quad * 16 + colq) * 8 + e] = f2bf(v);
        }
    } else {
        int r = blk - NG - 1024;             // vocab row 0..V_-1
        float v = (k < E_) ? emb[(size_t)r * E_ + k] : 0.0f;
        Ep[(size_t)r * KP + k] = f2bf(v);
    }
}

// ---------------- bf16 MFMA GEMM: gx = emb[sent] @ W^T + bias, permuted ------
// A-tiles gathered from the packed embedding table via token indices; both
// As and Bs staged with global_load_lds width=16 (no VGPR roundtrip).
__global__ __launch_bounds__(256, 3) void gemm_kernel(const unsigned short* __restrict__ Ep,
                                                      const int* __restrict__ sent,
                                                      const unsigned short* __restrict__ Bw,
                                                      const float* __restrict__ bF,
                                                      const float* __restrict__ bB,
                                                      unsigned short* __restrict__ C) {
    __shared__ __align__(16) unsigned short As[128 * 64];
    __shared__ __align__(16) unsigned short Bs[128 * 64];
    const int tid  = threadIdx.x;
    const int lane = tid & 63;
    const int wave = tid >> 6;
    const int wr = wave >> 1, wc = wave & 1;
    const int colL = lane & 15;
    const int mBase = blockIdx.y * 128;
    const int bx = blockIdx.x;
    const int d  = bx >> 2;
    const int w0 = (bx & 3) * 2;
    int toks[4];
    #pragma unroll
    for (int j = 0; j < 4; j++)
        toks[j] = sent[mBase + ((tid + 256 * j) >> 3)];
    f32x4 acc[4][4] = {};
    for (int k0 = 0; k0 < KP; k0 += 64) {
        #pragma unroll
        for (int j = 0; j < 4; j++) {
            int c   = tid + 256 * j;       // 16B chunk id 0..1023; LDS offset = c*16
            int col = (c & 7) * 8;
            __builtin_amdgcn_global_load_lds(
                (const void*)(Ep + (size_t)toks[j] * KP + k0 + col),
                (void*)((char*)As + c * 16), 16, 0, 0);
            int row = c >> 3;
            int ws = row >> 6, jj = (row >> 4) & 3, cc = row & 15;
            int srcrow = d * 512 + (8 * jj + w0 + ws) * 16 + cc;
            __builtin_amdgcn_global_load_lds(
                (const void*)(Bw + (size_t)srcrow * KP + k0 + col),
                (void*)((char*)Bs + c * 16), 16, 0, 0);
        }
        __syncthreads();
        #pragma unroll
        for (int ks = 0; ks < 2; ks++) {
            bf16x8 af[4], bfr[4];
            #pragma unroll
            for (int i = 0; i < 4; i++) {
                int arow = wr * 64 + i * 16 + colL;
                af[i]  = *(const bf16x8*)(As + arow * 64 + ks * 32 + (lane >> 4) * 8);
                int brow = wc * 64 + i * 16 + colL;
                bfr[i] = *(const bf16x8*)(Bs + brow * 64 + ks * 32 + (lane >> 4) * 8);
            }
            #pragma unroll
            for (int i = 0; i < 4; i++)
                #pragma unroll
                for (int n2 = 0; n2 < 4; n2++)
                    acc[i][n2] = __builtin_amdgcn_mfma_f32_16x16x32_bf16(af[i], bfr[n2], acc[i][n2], 0, 0, 0);
        }
        __syncthreads();
    }
    const float* bias_d = d ? bB : bF;
    float bj[4];
    #pragma unroll
    for (int n2 = 0; n2 < 4; n2++) bj[n2] = bias_d[(8 * n2 + w0 + wc) * 16 + colL];
    #pragma unroll
    for (int i = 0; i < 4; i++)
        #pragma unroll
        for (int r = 0; r < 4; r++) {
            int row = mBase + wr * 64 + i * 16 + (lane >> 4) * 4 + r;
            u16x4 v;
            #pragma unroll
            for (int n2 = 0; n2 < 4; n2++) v[n2] = f2bf(acc[i][n2][r] + bj[n2]);
            *(u16x4*)(C + (size_t)row * NG + d * 512 + (w0 + wc) * 64 + colL * 4) = v;
        }
}

// ---------------- MFMA LSTM recurrence + feats projection --------------------
// grid 128: block = (4 batch rows, dir). 576 threads = 9 waves (R7 structure).
__global__ __launch_bounds__(576, 1) void lstm_kernel(const unsigned short* __restrict__ gxP,
                                                      const unsigned short* __restrict__ Whp,
                                                      const int* __restrict__ seq_len,
                                                      const float* __restrict__ Wfc,
                                                      float* __restrict__ featsF,
                                                      float* __restrict__ featsB) {
    __shared__ __align__(16) unsigned short hL[2][16 * HSTR];
    __shared__ int Ls[4];
    __shared__ int maxLs;
    const int tid  = threadIdx.x;
    const int wave = tid >> 6;
    const int lane = tid & 63;
    const int col  = lane & 15;
    const int quad = lane >> 4;
    const int dir  = blockIdx.x & 1;
    const int b0   = (blockIdx.x >> 1) * 4;
    float* fOut = dir ? featsB : featsF;

    if (tid < 4) Ls[tid] = min(max(seq_len[b0 + tid], 1), T_);
    __syncthreads();
    if (tid == 0) { int m = 0; for (int i = 0; i < 4; i++) m = max(m, Ls[i]); maxLs = m; }
    __syncthreads();
    const int maxL = maxLs;
    const int Lq = Ls[quad];              // this lane's row length
    const int dNG = dir ? -NG : NG;

    bf16x8 Bf[4][4];                      // W_hh fragments (waves 0-7)
    bf16x8 Wf8[4];                        // W_fc fragments (wave 8)
    const unsigned short* rb = nullptr;   // this lane's gx base (step-0 pos)
    int ofs2 = 0;                         // element offset of the step-(s+2) load
    u16x4 gx0v = {}, gx1v = {};           // parity prefetch slots
    float* fb = nullptr;                  // wave-8 feats store base
    int foff = 0;

    if (wave < 8) {
        #pragma unroll
        for (int j = 0; j < 4; j++)
            #pragma unroll
            for (int kc = 0; kc < 4; kc++)
                Bf[j][kc] = *(const bf16x8*)(Whp +
                    ((((size_t)(dir * 8 + wave) * 4 + j) * 4 + kc) * 64 + lane) * 8);
        int row = b0 + quad;
        int p0 = dir ? (Lq - 1) : 0;
        rb = gxP + ((size_t)(row * T_ + p0)) * NG + dir * 512 + wave * 64 + col * 4;
        gx0v = *(const u16x4*)(rb);
        gx1v = *(const u16x4*)(rb + ((Lq > 1) ? dNG : 0));
        ofs2 = min(2, Lq - 1) * dNG;
    } else {
        #pragma unroll
        for (int kc = 0; kc < 4; kc++)
            #pragma unroll
            for (int e = 0; e < 8; e++) {
                float v = (col < NT_) ? Wfc[col * 256 + dir * H_ + kc * 32 + quad * 8 + e] : 0.0f;
                Wf8[kc][e] = (short)f2bf(v);
            }
        fb = fOut + (size_t)(b0 + quad) * T_ * NT_ + col;
        foff = (dir ? (Lq - 1) : 0) * NT_;
    }
    const int fd = dir ? -NT_ : NT_;

    float cst = 0.0f;
    bf16x8 Af[4];
    #pragma unroll
    for (int kc = 0; kc < 4; kc++)
        #pragma unroll
        for (int e = 0; e < 8; e++) Af[kc][e] = 0;   // h(-1) = 0

    auto step_body = [&](int s, u16x4& gxs, int par) {
        if (wave < 8) {
            f32x4 acc[4];
            #pragma unroll
            for (int j = 0; j < 4; j++) {
                acc[j][0] = bf2f(gxs[j]);            // gx (+bias) seed, real row
                acc[j][1] = 0.f; acc[j][2] = 0.f; acc[j][3] = 0.f;
            }
            // prefetch gx for step s+2 into the slot just consumed
            gxs = *(const u16x4*)(rb + ofs2);
            ofs2 = (s + 3 < Lq) ? ofs2 + dNG : ofs2;
            #pragma unroll
            for (int kc = 0; kc < 4; kc++)
                #pragma unroll
                for (int j = 0; j < 4; j++)
                    acc[j] = __builtin_amdgcn_mfma_f32_16x16x32_bf16(Af[kc], Bf[j][kc], acc[j], 0, 0, 0);
            float cn = sigf(acc[1][0]) * cst + sigf(acc[0][0]) * tanhfast(acc[2][0]);
            cst = cn;
            float hn = sigf(acc[3][0]) * tanhfast(cn);
            hL[par][(quad * 4) * HSTR + wave * 16 + col] = f2bf(hn);
        }
        barrier_lgkm();
        #pragma unroll
        for (int kc = 0; kc < 4; kc++)
            Af[kc] = *(const bf16x8*)(&hL[par][col * HSTR + kc * 32 + quad * 8]);
        if (wave == 8) {
            f32x4 fc = (f32x4){0.f, 0.f, 0.f, 0.f};
            #pragma unroll
            for (int kc = 0; kc < 4; kc++)
                fc = __builtin_amdgcn_mfma_f32_16x16x32_bf16(Af[kc], Wf8[kc], fc, 0, 0, 0);
            if (col < NT_ && s < Lq) fb[foff] = fc[0];
            foff += fd;
        }
    };

    for (int s = 0; s < maxL; s += 2) {
        step_body(s, gx0v, 0);
        if (s + 1 < maxL) step_body(s + 1, gx1v, 1);
    }
}

// ---------------- CRF: one wave per batch row, fused mean --------------------
// Alpha lives in a register (lane j owns alpha_j); redistribution via 13
// __shfl broadcasts per step -- no LDS, no barriers on the recurrence path.
// Feats staged one 16-step chunk ahead via float4 bulk loads (lanes 0..51).
__global__ __launch_bounds__(64) void crf_kernel(const float* __restrict__ fF,
                                                 const float* __restrict__ fB,
                                                 const float* __restrict__ bfc,
                                                 const float* __restrict__ trans,
                                                 const int* __restrict__ tags,
                                                 const int* __restrict__ seq_len,
                                                 float* __restrict__ out) {
    __shared__ __align__(16) float feat_lds[2 * 208];
    __shared__ float Tlds[NT_ * NT_];
    const int lane = threadIdx.x;
    const int b = blockIdx.x;
    const int Lb = min(max(seq_len[b], 1), T_);
    const float* fFb = fF + (size_t)b * T_ * NT_;
    const float* fBb = fB + (size_t)b * T_ * NT_;
    const int* tg = tags + (size_t)b * T_;

    for (int i = lane; i < NT_ * NT_; i += 64) Tlds[i] = trans[i];

    const int jc = min(lane, NT_ - 1);
    float Tj[NT_];
    #pragma unroll
    for (int i = 0; i < NT_; i++) Tj[i] = trans[jc * NT_ + i];
    const float bj  = bfc[jc];
    const float T10 = trans[10 * NT_ + jc];
    float alj = (jc == 0 && lane == 0) ? 0.0f : NEGV;   // alpha_j in-register

    // stage chunk 0
    const int e0 = lane * 4;
    const bool ldact = (lane < 52);
    float4 vF = {}, vB = {};
    if (ldact) { vF = *(const float4*)(fFb + e0); vB = *(const float4*)(fBb + e0); }

    #pragma unroll 1
    for (int c = 0; c < 12; ++c) {
        if (ldact) {
            float4 w;
            #pragma unroll
            for (int k = 0; k < 4; k++) {
                unsigned g = (unsigned)(c * 208 + e0 + k);
                unsigned t = g / 13u;
                float s = ((const float*)&vF)[k] + ((const float*)&vB)[k];
                ((float*)&w)[k] = (t < (unsigned)Lb) ? s : 0.0f;
            }
            *(float4*)&feat_lds[(c & 1) * 208 + e0] = w;
            if (c < 11) {
                vF = *(const float4*)(fFb + (c + 1) * 208 + e0);
                vB = *(const float4*)(fBb + (c + 1) * 208 + e0);
            }
        }
        barrier_lgkm();   // WAR on the other buffer protected one chunk later
        const int fbase = (c & 1) * 208;
        for (int tt = 0; tt < 16; ++tt) {
            float a0  = __shfl(alj, 0, 64),  a1  = __shfl(alj, 1, 64);
            float a2  = __shfl(alj, 2, 64),  a3  = __shfl(alj, 3, 64);
            float a4  = __shfl(alj, 4, 64),  a5  = __shfl(alj, 5, 64);
            float a6  = __shfl(alj, 6, 64),  a7  = __shfl(alj, 7, 64);
            float a8  = __shfl(alj, 8, 64),  a9  = __shfl(alj, 9, 64);
            float a10 = __shfl(alj, 10, 64), a11 = __shfl(alj, 11, 64);
            float a12 = __shfl(alj, 12, 64);
            float feat = feat_lds[fbase + tt * NT_ + jc];
            float v0 = a0 + Tj[0],  v1 = a1 + Tj[1],  v2 = a2 + Tj[2],  v3 = a3 + Tj[3];
            float v4 = a4 + Tj[4],  v5 = a5 + Tj[5],  v6 = a6 + Tj[6],  v7 = a7 + Tj[7];
            float v8 = a8 + Tj[8],  v9 = a9 + Tj[9],  v10 = a10 + Tj[10], v11 = a11 + Tj[11];
            float v12 = a12 + Tj[12];
            float p0 = fmaxf(v0, v1), p1 = fmaxf(v2, v3), p2 = fmaxf(v4, v5);
            float p3 = fmaxf(v6, v7), p4 = fmaxf(v8, v9), p5 = fmaxf(v10, v11);
            float q0 = fmaxf(p0, p1), q1 = fmaxf(p2, p3), q2 = fmaxf(p4, p5);
            float m = fmaxf(fmaxf(q0, q1), fmaxf(q2, v12));
            float e0_ = __expf(v0 - m),  e1_ = __expf(v1 - m),  e2_ = __expf(v2 - m);
            float e3_ = __expf(v3 - m),  e4_ = __expf(v4 - m),  e5_ = __expf(v5 - m);
            float e6_ = __expf(v6 - m),  e7_ = __expf(v7 - m),  e8_ = __expf(v8 - m);
            float e9_ = __expf(v9 - m),  e10_ = __expf(v10 - m), e11_ = __expf(v11 - m);
            float e12_ = __expf(v12 - m);
            float s0 = e0_ + e1_, s1 = e2_ + e3_, s2 = e4_ + e5_, s3 = e6_ + e7_;
            float s4 = e8_ + e9_, s5 = e10_ + e11_;
            float u0 = s0 + s1, u1 = s2 + s3, u2 = s4 + s5;
            float ss = (u0 + u1) + (u2 + e12_);
            alj = m + __logf(ss) + feat + bj;
        }
    }

    // gold score: t = lane, lane+64, lane+128
    float gp = 0.0f;
    #pragma unroll
    for (int u = 0; u < 3; ++u) {
        int t = lane + u * 64;
        int tt_ = tg[t];
        int pv = (t == 0) ? 0 : tg[t - 1];
        float e = bfc[tt_];
        if (t < Lb) e += fFb[t * NT_ + tt_] + fBb[t * NT_ + tt_];
        gp += Tlds[tt_ * NT_ + pv] + e;
    }
    #pragma unroll
    for (int o = 32; o > 0; o >>= 1) gp += __shfl_down(gp, o, 64);

    // fwd = LSE_j(alphaT[j] + trans[10][j])
    float vj = (lane < NT_) ? (alj + T10) : -3.0e38f;
    float mm = vj;
    #pragma unroll
    for (int o = 32; o > 0; o >>= 1) mm = fmaxf(mm, __shfl_down(mm, o, 64));
    mm = __shfl(mm, 0, 64);
    float se = (lane < NT_) ? __expf(vj - mm) : 0.0f;
    #pragma unroll
    for (int o = 32; o > 0; o >>= 1) se += __shfl_down(se, o, 64);
    if (lane == 0) {
        float fwd = mm + __logf(se);
        float gold = gp + Tlds[10 * NT_ + tg[T_ - 1]];
        atomicAdd(out, (fwd - gold) * (1.0f / 256.0f));
    }
}

extern "C" void kernel_launch(void* const* d_in, const int* in_sizes, int n_in,
                              void* d_out, int out_size, void* d_ws, size_t ws_size,
                              hipStream_t stream) {
    const int*   sentence  = (const int*)d_in[0];
    const int*   seq_len   = (const int*)d_in[1];
    const int*   tags      = (const int*)d_in[2];
    const float* embedding = (const float*)d_in[3];
    const float* W_ih_f    = (const float*)d_in[4];
    const float* W_hh_f    = (const float*)d_in[5];
    const float* b_f       = (const float*)d_in[6];
    const float* W_ih_b    = (const float*)d_in[7];
    const float* W_hh_b    = (const float*)d_in[8];
    const float* b_b       = (const float*)d_in[9];
    const float* W_fc      = (const float*)d_in[10];
    const float* b_fc      = (const float*)d_in[11];
    const float* trans     = (const float*)d_in[12];
    float* out = (float*)d_out;

    char* ws = (char*)d_ws;
    const size_t M = (size_t)B_ * T_;                   // 49152
    unsigned short* Wp  = (unsigned short*)(ws);                         // 655,360
    unsigned short* Ep  = (unsigned short*)(ws + 655360);                // 11626*320*2 = 7,440,640
    unsigned short* gx  = (unsigned short*)(ws + 8096000);               // 100,663,296
    float* featsF = (float*)(ws + 108759296);                            // 2,555,904
    float* featsB = (float*)(ws + 111315200);                            // 2,555,904
    unsigned short* Whp = (unsigned short*)(ws + 113871104);             // 262,144

    pack_kernel<<<NG + 1024 + V_, KP, 0, stream>>>(W_ih_f, W_ih_b, W_hh_f, W_hh_b,
                                                   embedding, Wp, Whp, Ep, out);
    dim3 gg(8, (int)(M / 128));
    gemm_kernel<<<gg, 256, 0, stream>>>(Ep, sentence, Wp, b_f, b_b, gx);
    lstm_kernel<<<128, 576, 0, stream>>>(gx, Whp, seq_len, W_fc, featsF, featsB);
    crf_kernel<<<B_, 64, 0, stream>>>(featsF, featsB, b_fc, trans, tags, seq_len, out);
}